// Round 5
// baseline (615.080 us; speedup 1.0000x reference)
//
#include <hip/hip_runtime.h>

#define S_STEPS 1024
#define BATCH 128
#define NQ 8
#define XW_B_STRIDE 24          // padded streams per batch (20 used)
#define XW_FLOATS (BATCH * XW_B_STRIDE * 1024)   // 3,145,728 floats
#define WT_ROW 32

// ---- helpers -----------------------------------------------------------
template<int CTRL>
__device__ __forceinline__ float dppf(float x) {
  return __int_as_float(__builtin_amdgcn_update_dpp(0, __float_as_int(x), CTRL, 0xf, 0xf, true));
}
template<int CTRL>
__device__ __forceinline__ int dppi(int x) {
  return __builtin_amdgcn_update_dpp(0, x, CTRL, 0xf, 0xf, true);
}
__device__ __forceinline__ float tanh01(float x) {   // x in [0,1]
  float t2 = x * x;
  return x * (t2 + 15.f) * __builtin_amdgcn_rcpf(fmaf(6.f, t2, 15.f));
}
__device__ __forceinline__ float tanh_c(float x) {
  x = fminf(fmaxf(x, -15.f), 15.f);
  float e = __builtin_amdgcn_exp2f(x * 2.88539008f);  // e^{2x}
  return (e - 1.f) * __builtin_amdgcn_rcpf(e + 1.f);
}

// ---- kernel 0: transpose W into WT[k][32] (20 used cols: c'' = g*5 + w')
__global__ void qlstm_wt(const float* __restrict__ Wf, const float* __restrict__ Wi,
                         const float* __restrict__ Wu, const float* __restrict__ Wo,
                         float* __restrict__ WT) {
  int idx = blockIdx.x * 256 + threadIdx.x;        // 0..5119
  if (idx >= 20 * 256) return;
  int k = idx & 255, cc = idx >> 8;                // cc = 0..19
  int g = cc / 5, w = cc % 5;
  int wire = (w < 2) ? w : w + 3;                  // 0,1,5,6,7
  const float* W = (g == 0) ? Wf : (g == 1) ? Wi : (g == 2) ? Wu : Wo;
  WT[k * WT_ROW + cc] = W[wire * 264 + k];
}

// ---- kernel 1: xw[(b*24 + g*5+w')*1024 + t] = bias + x[t,b,:]·W_g[wire,:256]
// wave = 64 t-consecutive rows of one batch column b; lane = row.
// x: per-lane sequential float4 stream; W: uniform (scalar) loads from WT.
__global__ __launch_bounds__(256) void qlstm_pre(
    const float* __restrict__ x, const float* __restrict__ WT,
    const float* __restrict__ bf, const float* __restrict__ bi,
    const float* __restrict__ bu, const float* __restrict__ bo,
    float* __restrict__ xw)
{
  const int wid = blockIdx.x * 4 + (threadIdx.x >> 6);   // 0..2047
  const int l   = threadIdx.x & 63;
  const int b   = wid & 127;
  const int t0  = (wid >> 7) * 64;
  const float4* px = (const float4*)(x + ((size_t)(t0 + l) * 128 + b) * 256);

  float acc[20];
#pragma unroll
  for (int g = 0; g < 4; ++g) {
    const float* bg = (g == 0) ? bf : (g == 1) ? bi : (g == 2) ? bu : bo;
    acc[g*5+0] = bg[0]; acc[g*5+1] = bg[1];
    acc[g*5+2] = bg[5]; acc[g*5+3] = bg[6]; acc[g*5+4] = bg[7];
  }

  float4 xv = px[0];
  for (int k4 = 0; k4 < 64; ++k4) {
    float4 xn = px[(k4 < 63) ? k4 + 1 : 63];
    float xs0 = xv.x, xs1 = xv.y, xs2 = xv.z, xs3 = xv.w;
    const float* wr = WT + (k4 * 4) * WT_ROW;          // uniform address
#pragma unroll
    for (int m = 0; m < 20; ++m) acc[m] = fmaf(xs0, wr[m], acc[m]);
#pragma unroll
    for (int m = 0; m < 20; ++m) acc[m] = fmaf(xs1, wr[WT_ROW + m], acc[m]);
#pragma unroll
    for (int m = 0; m < 20; ++m) acc[m] = fmaf(xs2, wr[2*WT_ROW + m], acc[m]);
#pragma unroll
    for (int m = 0; m < 20; ++m) acc[m] = fmaf(xs3, wr[3*WT_ROW + m], acc[m]);
    xv = xn;
  }

  float* xo = xw + (size_t)b * XW_B_STRIDE * 1024 + t0 + l;
#pragma unroll
  for (int m = 0; m < 20; ++m) xo[(size_t)m * 1024] = acc[m];   // coalesced over l
}

// ---- kernel 2: recurrence. 32 blocks x 64 thr; 4 batches/wave (16-lane rows).
// lane: r=lane&15, gate g=r>>2 (quad), k=r&3 -> handles indices k and k+4.
// Zero LDS: phase A/D = quad_perm splats, phase C = row_ror + probed select.
__global__ __launch_bounds__(64) void qlstm_seq(
    const float* __restrict__ xw,
    const float* __restrict__ Wf, const float* __restrict__ Wi,
    const float* __restrict__ Wu, const float* __restrict__ Wo,
    float* __restrict__ out)
{
  const int lane = threadIdx.x;
  const int r    = lane & 15;
  const int g    = r >> 2;
  const int k    = r & 3;
  const int b    = blockIdx.x * 4 + (lane >> 4);

  const int wA  = (k == 0) ? 0 : (k == 1) ? 5 : 7;    // dot wires
  const int wB  = (k == 0) ? 1 : (k == 1) ? 6 : 7;
  const int wpA = (k == 0) ? 0 : (k == 1) ? 2 : 4;    // stream idx w'
  const int wpB = (k == 0) ? 1 : (k == 1) ? 3 : 4;

  const float* Wg = (g == 0) ? Wf : (g == 1) ? Wi : (g == 2) ? Wu : Wo;
  float whA[8], whB[8];
#pragma unroll
  for (int j = 0; j < 8; ++j) {
    whA[j] = Wg[wA * 264 + 256 + j];
    whB[j] = Wg[wB * 264 + 256 + j];
  }

  // sign/offset masks for own index pair (idx k: B5=0; idx k+4: B5=1)
  const int B6 = (k >> 1) & 1, B7 = k & 1;
  const float s0 = B7 ? -1.f : 1.f,        o0 = B7 ? 1.f : 0.f;       // f0,f1
  const float s6 = B6 ? -1.f : 1.f,        o6 = B6 ? 1.f : 0.f;       // f6 (idx k)
  const float s7 = (B7^B6) ? -1.f : 1.f,   o7 = (B7^B6) ? 1.f : 0.f;  // f7

  // probe row_ror direction once (convention-proof cross-gate gather)
  const int g1 = dppi<0x124>(g), g2 = dppi<0x128>(g), g3 = dppi<0x12C>(g);
  const bool pf1 = (g1 == 0), pf2 = (g2 == 0), pf3 = (g3 == 0);
  const bool pi1 = (g1 == 1), pi2 = (g2 == 1), pi3 = (g3 == 1);
  const bool pu1 = (g1 == 2), pu2 = (g2 == 2), pu3 = (g3 == 2);
  const bool po1 = (g1 == 3), po2 = (g2 == 3), po3 = (g3 == 3);

  float h[8];
#pragma unroll
  for (int j = 0; j < 8; ++j) h[j] = 0.f;
  float cAcc = 0.f, cBcc = 0.f, hqA = 0.f, hqB = 0.f;

  const float* bxw = xw + (size_t)b * XW_B_STRIDE * 1024;
  const float4* pA = (const float4*)(bxw + (size_t)(g * 5 + wpA) * 1024);
  const float4* pB = (const float4*)(bxw + (size_t)(g * 5 + wpB) * 1024);
  float4 curA = pA[0], nxtA = pA[1];
  float4 curB = pB[0], nxtB = pB[1];

  const bool st = (g == 0);
  float* outp = out + (size_t)b * NQ;

#pragma unroll 1
  for (int T = 0; T < S_STEPS; T += 4) {
    int tp = (T >> 2) + 2; tp = (tp > 255) ? 255 : tp;
    float4 nnA = pA[tp], nnB = pB[tp];
#pragma unroll
    for (int u = 0; u < 4; ++u) {
      float pa = (u == 0) ? curA.x : (u == 1) ? curA.y : (u == 2) ? curA.z : curA.w;
      float pb = (u == 0) ? curB.x : (u == 1) ? curB.y : (u == 2) ? curB.z : curB.w;
#pragma unroll
      for (int j = 0; j < 8; ++j) {
        pa = fmaf(whA[j], h[j], pa);
        pb = fmaf(whB[j], h[j], pb);
      }
      float ccA = fmaf(0.5f, __builtin_amdgcn_cosf(pa * 0.15915494f), 0.5f);
      float ccB = fmaf(0.5f, __builtin_amdgcn_cosf(pb * 0.15915494f), 0.5f);

      // phase A: quad splats (deterministic)
      float C0 = dppf<0x00>(ccA);   // lane k=0, wire 0
      float C1 = dppf<0x00>(ccB);   // lane k=0, wire 1
      float C5 = dppf<0x55>(ccA);   // lane k=1, wire 5
      float C6 = dppf<0x55>(ccB);   // lane k=1, wire 6
      float C7 = dppf<0xAA>(ccA);   // lane k=2, wire 7

      // numerators for idx k (A) and k+4 (B): f5A=C5, f5B=1-C5, f6B=1-f6A
      float F0  = fmaf(s0, C0, o0);
      float F1  = fmaf(s0, C1, o0);
      float F7  = fmaf(s7, C7, o7);
      float F6A = fmaf(s6, C6, o6);
      float e7  = (F0 * F1) * F7;
      float dA  = C5 * F6A;
      float dB  = (1.f + dA) - (C5 + F6A);
      float pnumA = e7 * dA;
      float pnumB = e7 * dB;

      // denominator (shared within gate): s = Q01 + (P01-Q01)*T0, T1=1-T0
      float S0v = 1.f - C0, S1v = 1.f - C1;
      float P01 = C0 * C1,  Q01 = S0v * S1v;
      float d56 = C5 * C6;
      float U0  = fmaf(2.f, d56, 1.f - (C5 + C6));
      float S7v = 1.f - C7;
      float T0  = fmaf(C7 - S7v, U0, S7v);
      float sden = fmaf(P01 - Q01, T0, Q01);
      float rs  = __builtin_amdgcn_rcpf(sden);
      float pnA = pnumA * rs, pnB = pnumB * rs;

      // phase C: cross-gate gather via row_ror + probed select
      float a1 = dppf<0x124>(pnA), a2 = dppf<0x128>(pnA), a3 = dppf<0x12C>(pnA);
      float b1 = dppf<0x124>(pnB), b2 = dppf<0x128>(pnB), b3 = dppf<0x12C>(pnB);
      float fvA = pf1 ? a1 : pf2 ? a2 : pf3 ? a3 : pnA;
      float ivA = pi1 ? a1 : pi2 ? a2 : pi3 ? a3 : pnA;
      float uvA = pu1 ? a1 : pu2 ? a2 : pu3 ? a3 : pnA;
      float ovA = po1 ? a1 : po2 ? a2 : po3 ? a3 : pnA;
      float fvB = pf1 ? b1 : pf2 ? b2 : pf3 ? b3 : pnB;
      float ivB = pi1 ? b1 : pi2 ? b2 : pi3 ? b3 : pnB;
      float uvB = pu1 ? b1 : pu2 ? b2 : pu3 ? b3 : pnB;
      float ovB = po1 ? b1 : po2 ? b2 : po3 ? b3 : pnB;

      // LSTM for idx k and idx k+4
      float gvA = tanh01(uvA);
      cAcc = fmaf(fvA, cAcc, ivA * gvA);
      hqA  = ovA * tanh_c(cAcc);
      float gvB = tanh01(uvB);
      cBcc = fmaf(fvB, cBcc, ivB * gvB);
      hqB  = ovB * tanh_c(cBcc);

      // phase D: quad splats -> everyone gets h[0..7]
      h[0] = dppf<0x00>(hqA); h[1] = dppf<0x55>(hqA);
      h[2] = dppf<0xAA>(hqA); h[3] = dppf<0xFF>(hqA);
      h[4] = dppf<0x00>(hqB); h[5] = dppf<0x55>(hqB);
      h[6] = dppf<0xAA>(hqB); h[7] = dppf<0xFF>(hqB);

      if (st) {
        outp[(size_t)(T + u) * (BATCH * NQ) + k]     = hqA;
        outp[(size_t)(T + u) * (BATCH * NQ) + k + 4] = hqB;
      }
    }
    curA = nxtA; nxtA = nnA;
    curB = nxtB; nxtB = nnB;
  }
  if (st) {
    size_t o1 = (size_t)S_STEPS * BATCH * NQ + (size_t)b * NQ;
    out[o1 + k]     = hqA;
    out[o1 + k + 4] = hqB;
    size_t o2 = o1 + (size_t)BATCH * NQ;
    out[o2 + k]     = cAcc;
    out[o2 + k + 4] = cBcc;
  }
}

extern "C" void kernel_launch(void* const* d_in, const int* in_sizes, int n_in,
                              void* d_out, int out_size, void* d_ws, size_t ws_size,
                              hipStream_t stream) {
  const float* x  = (const float*)d_in[0];
  const float* Wf = (const float*)d_in[1];
  const float* bf = (const float*)d_in[2];
  const float* Wi = (const float*)d_in[3];
  const float* bi = (const float*)d_in[4];
  const float* Wu = (const float*)d_in[5];
  const float* bu = (const float*)d_in[6];
  const float* Wo = (const float*)d_in[7];
  const float* bo = (const float*)d_in[8];
  float* xw = (float*)d_ws;                 // 12.58 MB
  float* WT = xw + XW_FLOATS;               // 32 KB, inside previously-proven ws budget
  float* out = (float*)d_out;

  qlstm_wt <<<20, 256, 0, stream>>>(Wf, Wi, Wu, Wo, WT);
  qlstm_pre<<<512, 256, 0, stream>>>(x, WT, bf, bi, bu, bo, xw);
  qlstm_seq<<<32, 64, 0, stream>>>(xw, Wf, Wi, Wu, Wo, out);
}

// Round 6
// 457.706 us; speedup vs baseline: 1.3438x; 1.3438x over previous
//
#include <hip/hip_runtime.h>

#define S_STEPS 1024
#define BATCH 128
#define NQ 8
#define XW_FLOATS (BATCH * 32 * 1024)    // 16.78 MB in d_ws

using v2f     = float __attribute__((ext_vector_type(2)));
using frag_ab = __attribute__((ext_vector_type(8))) short;   // 8 bf16
using frag_cd = __attribute__((ext_vector_type(4))) float;   // 4 fp32

#define INV2PI 0.15915494309189535f

// ---- helpers -----------------------------------------------------------
template<int CTRL>
__device__ __forceinline__ float dppf(float x) {   // quad_perm splat (order-free)
  return __int_as_float(__builtin_amdgcn_update_dpp(0, __float_as_int(x), CTRL, 0xf, 0xf, true));
}
__device__ __forceinline__ float bperm(int addr, float v) {
  return __int_as_float(__builtin_amdgcn_ds_bpermute(addr, __float_as_int(v)));
}
__device__ __forceinline__ short f2bf(float f) {   // fp32 -> bf16 (RNE)
  unsigned u = __float_as_uint(f);
  return (short)((u + 0x7FFFu + ((u >> 16) & 1u)) >> 16);
}
__device__ __forceinline__ float bf2f(short h) {
  return __uint_as_float(((unsigned)(unsigned short)h) << 16);
}

// ---- kernel 1: MFMA GEMM.  xw[(b*32+c)*1024+t] = (bias_c + x[t,b,:]·Wc)/2π
// wave = 16b x 32c x 8t tiles; A/B hi-lo bf16 split (3 mfma) for fp32 accuracy.
__global__ __launch_bounds__(256) void qlstm_pre(
    const float* __restrict__ x,
    const float* __restrict__ Wf, const float* __restrict__ bf_,
    const float* __restrict__ Wi, const float* __restrict__ bi,
    const float* __restrict__ Wu, const float* __restrict__ bu,
    const float* __restrict__ Wo, const float* __restrict__ bo,
    float* __restrict__ xw)
{
  const int lane = threadIdx.x & 63;
  const int gid  = blockIdx.x * 4 + (threadIdx.x >> 6);   // 0..1023
  const int t0 = (gid >> 3) * 8;
  const int b0 = (gid & 7) * 16;
  const int m  = lane & 15;
  const int kg = lane >> 4;

  float bb[2];
  const float* wcol[2];
#pragma unroll
  for (int n = 0; n < 2; ++n) {
    int c = n * 16 + m;
    int g = c >> 3, w = c & 7;
    const float* bg = (g == 0) ? bf_ : (g == 1) ? bi : (g == 2) ? bu : bo;
    const float* Wg = (g == 0) ? Wf  : (g == 1) ? Wi : (g == 2) ? Wu : Wo;
    bb[n]   = bg[w] * INV2PI;
    wcol[n] = Wg + w * 264 + kg * 8;
  }

  frag_cd acc[8][2];
#pragma unroll
  for (int t = 0; t < 8; ++t)
#pragma unroll
    for (int n = 0; n < 2; ++n)
      acc[t][n] = (frag_cd){bb[n], bb[n], bb[n], bb[n]};

  const float* xbase = x + ((size_t)t0 * 128 + b0 + m) * 256 + kg * 8;

#pragma unroll 1
  for (int kk = 0; kk < 8; ++kk) {
    frag_ab bhi[2], blo[2];
#pragma unroll
    for (int n = 0; n < 2; ++n)
#pragma unroll
      for (int j = 0; j < 8; ++j) {
        float w = wcol[n][kk * 32 + j] * INV2PI;
        short h = f2bf(w);
        bhi[n][j] = h;
        blo[n][j] = f2bf(w - bf2f(h));
      }
#pragma unroll
    for (int t = 0; t < 8; ++t) {
      const float* xp = xbase + (size_t)t * 32768 + kk * 32;
      float4 xv0 = *(const float4*)(xp);
      float4 xv1 = *(const float4*)(xp + 4);
      float xf[8] = {xv0.x, xv0.y, xv0.z, xv0.w, xv1.x, xv1.y, xv1.z, xv1.w};
      frag_ab ahi, alo;
#pragma unroll
      for (int j = 0; j < 8; ++j) {
        short h = f2bf(xf[j]);
        ahi[j] = h;
        alo[j] = f2bf(xf[j] - bf2f(h));
      }
#pragma unroll
      for (int n = 0; n < 2; ++n) {
        acc[t][n] = __builtin_amdgcn_mfma_f32_16x16x32_bf16(ahi, bhi[n], acc[t][n], 0, 0, 0);
        acc[t][n] = __builtin_amdgcn_mfma_f32_16x16x32_bf16(alo, bhi[n], acc[t][n], 0, 0, 0);
        acc[t][n] = __builtin_amdgcn_mfma_f32_16x16x32_bf16(ahi, blo[n], acc[t][n], 0, 0, 0);
      }
    }
  }

  // C/D: col = lane&15 (= c within n-tile), row = kg*4+reg (= b offset)
#pragma unroll
  for (int n = 0; n < 2; ++n)
#pragma unroll
    for (int rho = 0; rho < 4; ++rho) {
      float* op = xw + ((size_t)((b0 + kg * 4 + rho) * 32 + n * 16 + m)) * 1024 + t0;
      float4 v0 = {acc[0][n][rho], acc[1][n][rho], acc[2][n][rho], acc[3][n][rho]};
      float4 v1 = {acc[4][n][rho], acc[5][n][rho], acc[6][n][rho], acc[7][n][rho]};
      *(float4*)op = v0;
      *(float4*)(op + 4) = v1;
    }
}

// ---- kernel 2: recurrence. 32 blocks x 64 thr; 4 batches/wave, 16 lanes/batch.
// lane: g = quad (gate), k = lane&3 -> indices k, k+4.  Phase A/D = quad_perm
// splats; phase C = ds_bpermute (no selects).  Everything pre-scaled by 1/2π.
__global__ __launch_bounds__(64) void qlstm_seq(
    const float* __restrict__ xw,
    const float* __restrict__ Wf, const float* __restrict__ Wi,
    const float* __restrict__ Wu, const float* __restrict__ Wo,
    float* __restrict__ out)
{
  const int lane = threadIdx.x;
  const int r = lane & 15, g = r >> 2, k = r & 3;
  const int b = blockIdx.x * 4 + (lane >> 4);
  const int B6 = (k >> 1) & 1, B7 = k & 1;
  const bool isB7 = (B7 != 0);
  const float s6 = B6 ? -1.f : 1.f,        o6 = B6 ? 1.f : 0.f;
  const float s7 = (B7^B6) ? -1.f : 1.f,   o7 = (B7^B6) ? 1.f : 0.f;
  const int wA = (k == 0) ? 0 : (k == 1) ? 5 : 7;
  const int wB = (k == 0) ? 1 : (k == 1) ? 6 : 7;

  const float* Wg = (g == 0) ? Wf : (g == 1) ? Wi : (g == 2) ? Wu : Wo;
  v2f whA2[4], whB2[4];
#pragma unroll
  for (int j2 = 0; j2 < 4; ++j2) {
    whA2[j2] = (v2f){Wg[wA*264+256+2*j2] * INV2PI, Wg[wA*264+256+2*j2+1] * INV2PI};
    whB2[j2] = (v2f){Wg[wB*264+256+2*j2] * INV2PI, Wg[wB*264+256+2*j2+1] * INV2PI};
  }

  // bpermute source addresses (bytes): lane (b^,g',k) for g'=0..3
  const int aF = (((lane & 48) | k) << 2);
  const int aI = aF + 16, aU = aF + 32, aO = aF + 48;

  v2f h2[4];
#pragma unroll
  for (int j = 0; j < 4; ++j) h2[j] = (v2f){0.f, 0.f};
  float cA = 0.f, cB = 0.f, hqA = 0.f, hqB = 0.f;

  const float* bxw = xw + (size_t)b * 32768;
  const float4* pA = (const float4*)(bxw + (size_t)(g * 8 + wA) * 1024);
  const float4* pB = (const float4*)(bxw + (size_t)(g * 8 + wB) * 1024);
  float4 curA = pA[0], nxtA = pA[1];
  float4 curB = pB[0], nxtB = pB[1];

  const int soff = b * 8 + r;     // valid for r<8 (= g*4+k)
  float houtS[16];

#pragma unroll 1
  for (int Tb = 0; Tb < S_STEPS; Tb += 16) {
#pragma unroll
    for (int sg = 0; sg < 4; ++sg) {
      int gi = (Tb >> 2) + sg;
      int tp = gi + 2; tp = (tp > 255) ? 255 : tp;
      float4 nnA = pA[tp], nnB = pB[tp];
#pragma unroll
      for (int u = 0; u < 4; ++u) {
        float xa = (u==0)?curA.x:(u==1)?curA.y:(u==2)?curA.z:curA.w;
        float xb = (u==0)?curB.x:(u==1)?curB.y:(u==2)?curB.z:curB.w;
        v2f accA = whA2[0]*h2[0]; accA = whA2[1]*h2[1] + accA;
        accA = whA2[2]*h2[2] + accA; accA = whA2[3]*h2[3] + accA;
        v2f accB = whB2[0]*h2[0]; accB = whB2[1]*h2[1] + accB;
        accB = whB2[2]*h2[2] + accB; accB = whB2[3]*h2[3] + accB;
        float pa = (xa + accA.x) + accA.y;     // revolutions
        float pb = (xb + accB.x) + accB.y;
        float ccA = fmaf(0.5f, __builtin_amdgcn_cosf(pa), 0.5f);
        float ccB = fmaf(0.5f, __builtin_amdgcn_cosf(pb), 0.5f);

        // phase A: quad splats (wire cos^2, shared within gate)
        float C0 = dppf<0x00>(ccA), C1 = dppf<0x00>(ccB);
        float C5 = dppf<0x55>(ccA), C6 = dppf<0x55>(ccB);
        float C7 = dppf<0xAA>(ccA);

        // numerators + shared denominator
        float S0v = 1.f - C0, S1v = 1.f - C1;
        float P01 = C0 * C1, Q01 = S0v * S1v;
        float sel01 = isB7 ? Q01 : P01;        // = F0*F1
        float F7  = fmaf(s7, C7, o7);
        float F6A = fmaf(s6, C6, o6);
        float e7  = sel01 * F7;
        float dA  = C5 * F6A;
        float dB  = (1.f + dA) - (C5 + F6A);   // (1-C5)(1-F6A)
        float d56 = C5 * C6;
        float U0  = fmaf(2.f, d56, 1.f - (C5 + C6));
        float S7v = 1.f - C7;
        float T0  = fmaf(fmaf(2.f, C7, -1.f), U0, S7v);
        float sden = fmaf(P01 - Q01, T0, Q01);
        float es  = e7 * __builtin_amdgcn_rcpf(sden);
        float pnA = es * dA, pnB = es * dB;

        // phase C: cross-gate all-gather via bpermute
        float fvA = bperm(aF, pnA), ivA = bperm(aI, pnA);
        float uvA = bperm(aU, pnA), ovA = bperm(aO, pnA);
        float fvB = bperm(aF, pnB), ivB = bperm(aI, pnB);
        float uvB = bperm(aU, pnB), ovB = bperm(aO, pnB);

        // LSTM, index k (A) and k+4 (B)
        float t2A = uvA * uvA;
        float gvA = uvA * (t2A + 15.f) * __builtin_amdgcn_rcpf(fmaf(6.f, t2A, 15.f));
        cA = fmaf(fvA, cA, ivA * gvA);
        float eA = __builtin_amdgcn_exp2f(fminf(cA, 15.f) * 2.88539008f);
        hqA = ovA * fmaf(-2.f, __builtin_amdgcn_rcpf(eA + 1.f), 1.f);
        float t2B = uvB * uvB;
        float gvB = uvB * (t2B + 15.f) * __builtin_amdgcn_rcpf(fmaf(6.f, t2B, 15.f));
        cB = fmaf(fvB, cB, ivB * gvB);
        float eB = __builtin_amdgcn_exp2f(fminf(cB, 15.f) * 2.88539008f);
        hqB = ovB * fmaf(-2.f, __builtin_amdgcn_rcpf(eB + 1.f), 1.f);

        // phase D: quad splats -> h pairs (h0..h7)
        h2[0].x = dppf<0x00>(hqA); h2[0].y = dppf<0x55>(hqA);
        h2[1].x = dppf<0xAA>(hqA); h2[1].y = dppf<0xFF>(hqA);
        h2[2].x = dppf<0x00>(hqB); h2[2].y = dppf<0x55>(hqB);
        h2[3].x = dppf<0xAA>(hqB); h2[3].y = dppf<0xFF>(hqB);

        houtS[sg * 4 + u] = (g == 0) ? hqA : hqB;
      }
      curA = nxtA; nxtA = nnA;
      curB = nxtB; nxtB = nnB;
    }
    if (r < 8) {
      float* op = out + (size_t)Tb * (BATCH * NQ) + soff;
#pragma unroll
      for (int tt = 0; tt < 16; ++tt)
        op[(size_t)tt * (BATCH * NQ)] = houtS[tt];
    }
  }
  if (r < 8) {
    size_t o1 = (size_t)S_STEPS * BATCH * NQ + soff;
    out[o1] = (g == 0) ? hqA : hqB;                       // h_n
    out[o1 + (size_t)BATCH * NQ] = (g == 0) ? cA : cB;    // c_n
  }
}

extern "C" void kernel_launch(void* const* d_in, const int* in_sizes, int n_in,
                              void* d_out, int out_size, void* d_ws, size_t ws_size,
                              hipStream_t stream) {
  const float* x  = (const float*)d_in[0];
  const float* Wf = (const float*)d_in[1];
  const float* bf = (const float*)d_in[2];
  const float* Wi = (const float*)d_in[3];
  const float* bi = (const float*)d_in[4];
  const float* Wu = (const float*)d_in[5];
  const float* bu = (const float*)d_in[6];
  const float* Wo = (const float*)d_in[7];
  const float* bo = (const float*)d_in[8];
  float* xw  = (float*)d_ws;               // (128*32, 1024) floats = 16.78 MB
  float* out = (float*)d_out;

  qlstm_pre<<<256, 256, 0, stream>>>(x, Wf, bf, Wi, bi, Wu, bu, Wo, bo, xw);
  qlstm_seq<<<32, 64, 0, stream>>>(xw, Wf, Wi, Wu, Wo, out);
}